// Round 1
// baseline (12385.108 us; speedup 1.0000x reference)
//
#include <hip/hip_runtime.h>
#include <math.h>

#define C 32
#define H0 384
#define W0 640
#define H1 192
#define W1 320
#define H2 96
#define W2 160
#define NP1 (H1*W1)   /* 61440 */
#define NP2 (H2*W2)   /* 15360 */
#define ND  48        /* MAX_DISP/4 */

// ---------------- encoder kernels ----------------

// 7x7 stride2 pad3 conv, 3->32 ch, with input normalization 2*(x/255)-1 fused
__global__ void conv7s2_kernel(const float* __restrict__ img, const float* __restrict__ w,
                               const float* __restrict__ b, float* __restrict__ out) {
    __shared__ float lw[3*49];
    int co = blockIdx.x / (NP1/256);
    int sp = (blockIdx.x % (NP1/256)) * 256 + threadIdx.x;
    for (int i = threadIdx.x; i < 147; i += 256) lw[i] = w[co*147 + i];
    __syncthreads();
    int oy = sp / W1, ox = sp % W1;
    float acc = b[co];
    for (int ci = 0; ci < 3; ++ci) {
        const float* ip = img + ci*H0*W0;
        for (int ky = 0; ky < 7; ++ky) {
            int iy = 2*oy - 3 + ky;
            if ((unsigned)iy >= (unsigned)H0) continue;
            const float* row = ip + iy*W0;
            for (int kx = 0; kx < 7; ++kx) {
                int ix = 2*ox - 3 + kx;
                if ((unsigned)ix >= (unsigned)W0) continue;
                float v = row[ix] * (2.0f/255.0f) - 1.0f;
                acc += lw[ci*49 + ky*7 + kx] * v;
            }
        }
    }
    out[co*NP1 + sp] = acc;
}

// per-channel mean / rsqrt(var+eps); one block per channel
__global__ void chan_stats_kernel(const float* __restrict__ x, int N, float* __restrict__ stats) {
    __shared__ float ssum[256], ssq[256];
    int c = blockIdx.x;
    const float* p = x + (size_t)c*N;
    float s = 0.f, s2 = 0.f;
    for (int i = threadIdx.x; i < N; i += 256) { float v = p[i]; s += v; s2 += v*v; }
    ssum[threadIdx.x] = s; ssq[threadIdx.x] = s2;
    __syncthreads();
    for (int o = 128; o > 0; o >>= 1) {
        if (threadIdx.x < o) { ssum[threadIdx.x] += ssum[threadIdx.x+o]; ssq[threadIdx.x] += ssq[threadIdx.x+o]; }
        __syncthreads();
    }
    if (threadIdx.x == 0) {
        float m = ssum[0] / (float)N;
        float v = ssq[0] / (float)N - m*m;
        stats[c] = m;
        stats[C + c] = rsqrtf(v + 1e-5f);
    }
}

// x = relu((x - mean[c]) * rstd[c]), in place; grid covers C*N (divisible by 256)
__global__ void norm_relu_kernel(float* __restrict__ x, const float* __restrict__ stats, int N) {
    int idx = blockIdx.x*256 + threadIdx.x;
    int c = idx / N;
    float v = x[idx];
    v = (v - stats[c]) * stats[C + c];
    x[idx] = fmaxf(v, 0.0f);
}

// 3x3 stride2 pad1 conv, 32->32
__global__ void conv3s2_kernel(const float* __restrict__ in, const float* __restrict__ w,
                               const float* __restrict__ b, float* __restrict__ out) {
    __shared__ float lw[C*9];
    int co = blockIdx.x / (NP2/256);
    int sp = (blockIdx.x % (NP2/256)) * 256 + threadIdx.x;
    for (int i = threadIdx.x; i < C*9; i += 256) lw[i] = w[co*C*9 + i];
    __syncthreads();
    int oy = sp / W2, ox = sp % W2;
    float acc = b[co];
    for (int ci = 0; ci < C; ++ci) {
        const float* ip = in + ci*NP1;
        for (int ky = 0; ky < 3; ++ky) {
            int iy = 2*oy - 1 + ky;
            if ((unsigned)iy >= (unsigned)H1) continue;
            const float* row = ip + iy*W1;
            for (int kx = 0; kx < 3; ++kx) {
                int ix = 2*ox - 1 + kx;
                if ((unsigned)ix >= (unsigned)W1) continue;
                acc += lw[ci*9 + ky*3 + kx] * row[ix];
            }
        }
    }
    out[co*NP2 + sp] = acc;
}

// 1x1 conv 32->32, optional tanh (mode=1)
__global__ void conv1x1_kernel(const float* __restrict__ in, const float* __restrict__ w,
                               const float* __restrict__ b, float* __restrict__ out, int mode) {
    __shared__ float lw[C];
    int co = blockIdx.x / (NP2/256);
    int sp = (blockIdx.x % (NP2/256))*256 + threadIdx.x;
    if (threadIdx.x < C) lw[threadIdx.x] = w[co*C + threadIdx.x];
    __syncthreads();
    float acc = b[co];
    for (int ci = 0; ci < C; ++ci) acc += lw[ci] * in[ci*NP2 + sp];
    if (mode) acc = tanhf(acc);
    out[co*NP2 + sp] = acc;
}

// ---------------- GRU loop kernels ----------------

// combine z/r weights: hx = [h, h, feat] -> 64-ch weights (w[:,0:32]+w[:,32:64] || w[:,64:96])
__global__ void prep_zr_weights(const float* __restrict__ wz, const float* __restrict__ wr,
                                float* __restrict__ wzc, float* __restrict__ wrc) {
    int idx = blockIdx.x*256 + threadIdx.x;  // 32*64*9 = 18432
    if (idx >= 32*64*9) return;
    int k = idx % 9;
    int cin = (idx / 9) % 64;
    int co = idx / (9*64);
    int base = co*96*9;
    if (cin < 32) {
        wzc[idx] = wz[base + cin*9 + k] + wz[base + (cin+32)*9 + k];
        wrc[idx] = wr[base + cin*9 + k] + wr[base + (cin+32)*9 + k];
    } else {
        wzc[idx] = wz[base + (cin+32)*9 + k];
        wrc[idx] = wr[base + (cin+32)*9 + k];
    }
}

// feat = A*f1 + B*f2 + Cw*(f1*f2) + b  (all 1x1)
__global__ void feat_kernel(const float* __restrict__ fmap1, const float* __restrict__ fmap2,
                            const float* __restrict__ wa, const float* __restrict__ wb,
                            const float* __restrict__ wc, const float* __restrict__ bc,
                            float* __restrict__ feat, int d, int nblk) {
    __shared__ float la[C], lb[C], lc[C];
    int co = blockIdx.x / nblk;
    int sp = (blockIdx.x % nblk)*256 + threadIdx.x;
    if (threadIdx.x < C) {
        la[threadIdx.x] = wa[co*C + threadIdx.x];
        lb[threadIdx.x] = wb[co*C + threadIdx.x];
        lc[threadIdx.x] = wc[co*C + threadIdx.x];
    }
    __syncthreads();
    int Wd = W2 - d;
    int nsp = H2*Wd;
    if (sp >= nsp) return;
    int y = sp / Wd, x = sp % Wd;
    float acc = bc[co];
    for (int ci = 0; ci < C; ++ci) {
        float f1 = fmap1[ci*NP2 + y*W2 + x + d];
        float f2 = fmap2[ci*NP2 + y*W2 + x];
        acc += la[ci]*f1 + lb[ci]*f2 + lc[ci]*(f1*f2);
    }
    feat[co*NP2 + y*W2 + x] = acc;
}

// z,r via 3x3 conv with combined 64-ch weights over [h, feat]; writes z and r*h
__global__ void zr_kernel(const float* __restrict__ hidden, const float* __restrict__ feat,
                          const float* __restrict__ wzc, const float* __restrict__ wrc,
                          const float* __restrict__ bz, const float* __restrict__ br,
                          float* __restrict__ zbuf, float* __restrict__ rh,
                          int d, int nblk) {
    __shared__ float lwz[64*9], lwr[64*9];
    int co = blockIdx.x / nblk;
    int sp = (blockIdx.x % nblk)*256 + threadIdx.x;
    for (int i = threadIdx.x; i < 576; i += 256) { lwz[i] = wzc[co*576+i]; lwr[i] = wrc[co*576+i]; }
    __syncthreads();
    int Wd = W2 - d;
    int nsp = H2*Wd;
    if (sp >= nsp) return;
    int y = sp / Wd, x = sp % Wd;
    float az = bz[co], ar = br[co];
    for (int cin = 0; cin < 64; ++cin) {
        const float* ip = (cin < 32) ? (hidden + cin*NP2 + d) : (feat + (cin-32)*NP2);
        const float* wpz = lwz + cin*9;
        const float* wpr = lwr + cin*9;
        for (int dy = 0; dy < 3; ++dy) {
            int ys = y + dy - 1;
            if ((unsigned)ys >= (unsigned)H2) continue;
            const float* row = ip + ys*W2;
            for (int dx = 0; dx < 3; ++dx) {
                int xs = x + dx - 1;
                if ((unsigned)xs >= (unsigned)Wd) continue;
                float v = row[xs];
                az += wpz[dy*3+dx]*v;
                ar += wpr[dy*3+dx]*v;
            }
        }
    }
    float z = 1.0f/(1.0f + expf(-az));
    float r = 1.0f/(1.0f + expf(-ar));
    float h = hidden[co*NP2 + y*W2 + x + d];
    zbuf[co*NP2 + y*W2 + x] = z;
    rh[co*NP2 + y*W2 + x] = r*h;
}

// q = tanh(conv3x3([r*h, h, feat], wq) + bq)
__global__ void q_kernel(const float* __restrict__ hidden, const float* __restrict__ feat,
                         const float* __restrict__ rh, const float* __restrict__ wq,
                         const float* __restrict__ bq, float* __restrict__ qbuf,
                         int d, int nblk) {
    __shared__ float lw[96*9];
    int co = blockIdx.x / nblk;
    int sp = (blockIdx.x % nblk)*256 + threadIdx.x;
    for (int i = threadIdx.x; i < 864; i += 256) lw[i] = wq[co*864 + i];
    __syncthreads();
    int Wd = W2 - d;
    int nsp = H2*Wd;
    if (sp >= nsp) return;
    int y = sp / Wd, x = sp % Wd;
    float acc = bq[co];
    for (int cin = 0; cin < 96; ++cin) {
        const float* ip;
        if (cin < 32)      ip = rh + cin*NP2;
        else if (cin < 64) ip = hidden + (cin-32)*NP2 + d;
        else               ip = feat + (cin-64)*NP2;
        const float* wp = lw + cin*9;
        for (int dy = 0; dy < 3; ++dy) {
            int ys = y + dy - 1;
            if ((unsigned)ys >= (unsigned)H2) continue;
            const float* row = ip + ys*W2;
            for (int dx = 0; dx < 3; ++dx) {
                int xs = x + dx - 1;
                if ((unsigned)xs >= (unsigned)Wd) continue;
                acc += wp[dy*3+dx] * row[xs];
            }
        }
    }
    qbuf[co*NP2 + y*W2 + x] = tanhf(acc);
}

// hidden[:, :, d:] = (1-z)*h + z*q  (pointwise, in place)
__global__ void update_kernel(float* __restrict__ hidden, const float* __restrict__ zbuf,
                              const float* __restrict__ qbuf, int d, int total) {
    int idx = blockIdx.x*256 + threadIdx.x;
    if (idx >= total) return;
    int Wd = W2 - d;
    int x = idx % Wd;
    int rest = idx / Wd;          // co*H2 + y
    int off = rest*W2 + x;
    float h = hidden[off + d];
    float z = zbuf[off];
    float q = qbuf[off];
    hidden[off + d] = (1.0f - z)*h + z*q;
}

// ---------------- disparity head ----------------

__global__ void disp1_kernel(const float* __restrict__ hidden, const float* __restrict__ w,
                             const float* __restrict__ b, float* __restrict__ out) {
    __shared__ float lw[C*9];
    int co = blockIdx.x / (NP2/256);
    int sp = (blockIdx.x % (NP2/256))*256 + threadIdx.x;
    for (int i = threadIdx.x; i < C*9; i += 256) lw[i] = w[co*C*9 + i];
    __syncthreads();
    int y = sp / W2, x = sp % W2;
    float acc = b[co];
    for (int ci = 0; ci < C; ++ci) {
        const float* ip = hidden + ci*NP2;
        for (int dy = 0; dy < 3; ++dy) {
            int ys = y+dy-1; if ((unsigned)ys >= (unsigned)H2) continue;
            const float* row = ip + ys*W2;
            for (int dx = 0; dx < 3; ++dx) {
                int xs = x+dx-1; if ((unsigned)xs >= (unsigned)W2) continue;
                acc += lw[ci*9+dy*3+dx] * row[xs];
            }
        }
    }
    out[co*NP2 + sp] = fmaxf(acc, 0.0f);
}

__global__ void disp2_kernel(const float* __restrict__ in, const float* __restrict__ w,
                             const float* __restrict__ b, float* __restrict__ out) {
    __shared__ float lw[64*9];
    int sp = blockIdx.x*256 + threadIdx.x;
    for (int i = threadIdx.x; i < 576; i += 256) lw[i] = w[i];
    __syncthreads();
    int y = sp / W2, x = sp % W2;
    float acc = b[0];
    for (int ci = 0; ci < 64; ++ci) {
        const float* ip = in + ci*NP2;
        for (int dy = 0; dy < 3; ++dy) {
            int ys = y+dy-1; if ((unsigned)ys >= (unsigned)H2) continue;
            const float* row = ip + ys*W2;
            for (int dx = 0; dx < 3; ++dx) {
                int xs = x+dx-1; if ((unsigned)xs >= (unsigned)W2) continue;
                acc += lw[ci*9+dy*3+dx] * row[xs];
            }
        }
    }
    out[sp] = -acc;
}

// ---------------- launch ----------------

extern "C" void kernel_launch(void* const* d_in, const int* in_sizes, int n_in,
                              void* d_out, int out_size, void* d_ws, size_t ws_size,
                              hipStream_t stream) {
    const float* image1   = (const float*)d_in[0];
    const float* image2   = (const float*)d_in[1];
    const float* fnet_w1  = (const float*)d_in[2];
    const float* fnet_b1  = (const float*)d_in[3];
    const float* fnet_w2  = (const float*)d_in[4];
    const float* fnet_b2  = (const float*)d_in[5];
    const float* fnet_w3  = (const float*)d_in[6];
    const float* fnet_b3  = (const float*)d_in[7];
    const float* cnet_w1  = (const float*)d_in[8];
    const float* cnet_b1  = (const float*)d_in[9];
    const float* cnet_w2  = (const float*)d_in[10];
    const float* cnet_b2  = (const float*)d_in[11];
    const float* cnet_w3  = (const float*)d_in[12];
    const float* cnet_b3  = (const float*)d_in[13];
    const float* bform_a  = (const float*)d_in[14];
    const float* bform_b  = (const float*)d_in[15];
    const float* bform_cd_w = (const float*)d_in[16];
    const float* bform_cd_b = (const float*)d_in[17];
    const float* gru_wz   = (const float*)d_in[18];
    const float* gru_bz   = (const float*)d_in[19];
    const float* gru_wr   = (const float*)d_in[20];
    const float* gru_br   = (const float*)d_in[21];
    const float* gru_wq   = (const float*)d_in[22];
    const float* gru_bq   = (const float*)d_in[23];
    const float* disp_w1  = (const float*)d_in[24];
    const float* disp_b1  = (const float*)d_in[25];
    const float* disp_w2  = (const float*)d_in[26];
    const float* disp_b2  = (const float*)d_in[27];

    float* ws = (float*)d_ws;
    size_t off = 0;
    float* e1     = ws + off; off += (size_t)32*NP1;
    float* e2     = ws + off; off += (size_t)32*NP2;
    float* fmap1  = ws + off; off += (size_t)32*NP2;
    float* fmap2  = ws + off; off += (size_t)32*NP2;
    float* hidden = ws + off; off += (size_t)32*NP2;
    float* feat   = ws + off; off += (size_t)32*NP2;
    float* zbuf   = ws + off; off += (size_t)32*NP2;
    float* rh     = ws + off; off += (size_t)32*NP2;
    float* qbuf   = ws + off; off += (size_t)32*NP2;
    float* disp1  = ws + off; off += (size_t)64*NP2;
    float* stats  = ws + off; off += 64;
    float* wzc    = ws + off; off += 32*64*9;
    float* wrc    = ws + off; off += 32*64*9;

    // --- encoders (B=1: inorm == bnorm) ---
    auto encoder = [&](const float* img, const float* w1, const float* b1,
                       const float* w2, const float* b2,
                       const float* w3, const float* b3, float* dst, int mode) {
        conv7s2_kernel<<<32*(NP1/256), 256, 0, stream>>>(img, w1, b1, e1);
        chan_stats_kernel<<<C, 256, 0, stream>>>(e1, NP1, stats);
        norm_relu_kernel<<<(C*NP1)/256, 256, 0, stream>>>(e1, stats, NP1);
        conv3s2_kernel<<<32*(NP2/256), 256, 0, stream>>>(e1, w2, b2, e2);
        chan_stats_kernel<<<C, 256, 0, stream>>>(e2, NP2, stats);
        norm_relu_kernel<<<(C*NP2)/256, 256, 0, stream>>>(e2, stats, NP2);
        conv1x1_kernel<<<32*(NP2/256), 256, 0, stream>>>(e2, w3, b3, dst, mode);
    };
    encoder(image1, fnet_w1, fnet_b1, fnet_w2, fnet_b2, fnet_w3, fnet_b3, fmap1, 0);
    encoder(image2, fnet_w1, fnet_b1, fnet_w2, fnet_b2, fnet_w3, fnet_b3, fmap2, 0);
    encoder(image1, cnet_w1, cnet_b1, cnet_w2, cnet_b2, cnet_w3, cnet_b3, hidden, 1);

    prep_zr_weights<<<(32*64*9 + 255)/256, 256, 0, stream>>>(gru_wz, gru_wr, wzc, wrc);

    // --- sequential GRU sweep over disparities ---
    for (int d = 0; d < ND; ++d) {
        int Wd = W2 - d;
        int nsp = H2*Wd;
        int nblk = (nsp + 255)/256;
        feat_kernel<<<32*nblk, 256, 0, stream>>>(fmap1, fmap2, bform_a, bform_b,
                                                 bform_cd_w, bform_cd_b, feat, d, nblk);
        zr_kernel<<<32*nblk, 256, 0, stream>>>(hidden, feat, wzc, wrc, gru_bz, gru_br,
                                               zbuf, rh, d, nblk);
        q_kernel<<<32*nblk, 256, 0, stream>>>(hidden, feat, rh, gru_wq, gru_bq, qbuf, d, nblk);
        int tot = 32*nsp;
        update_kernel<<<(tot + 255)/256, 256, 0, stream>>>(hidden, zbuf, qbuf, d, tot);
    }

    // --- disparity head ---
    disp1_kernel<<<64*(NP2/256), 256, 0, stream>>>(hidden, disp_w1, disp_b1, disp1);
    disp2_kernel<<<NP2/256, 256, 0, stream>>>(disp1, disp_w2, disp_b2, (float*)d_out);
}

// Round 2
// 11393.559 us; speedup vs baseline: 1.0870x; 1.0870x over previous
//
#include <hip/hip_runtime.h>
#include <math.h>

#define H0 384
#define W0 640
#define H1 192
#define W1 320
#define H2 96
#define W2 160
#define NP1 (H1*W1)   /* 61440 */
#define NP2 (H2*W2)   /* 15360 */
#define ND  48        /* MAX_DISP/4 */

// ---------------- prep kernels ----------------

__global__ void zero_stats_kernel(float* __restrict__ s, int n) {
    int i = blockIdx.x*256 + threadIdx.x;
    if (i < n) s[i] = 0.f;
}

// out[(ci*K + k)*CO + co] = in[(co*CI + ci)*K + k]
__global__ void transpose_w_kernel(const float* __restrict__ in, float* __restrict__ out,
                                   int CI, int K, int CO) {
    int idx = blockIdx.x*256 + threadIdx.x;
    int total = CI*K*CO;
    if (idx >= total) return;
    int co = idx % CO;
    int t  = idx / CO;
    int k  = t % K;
    int ci = t / K;
    out[idx] = in[(co*CI + ci)*K + k];
}

// combined (hx = [h,h,feat]) z/r weights, transposed to [ci<64][9][32]
__global__ void prep_zr_t_kernel(const float* __restrict__ wz, const float* __restrict__ wr,
                                 float* __restrict__ wzt, float* __restrict__ wrt) {
    int idx = blockIdx.x*256 + threadIdx.x;  // 64*9*32 = 18432
    if (idx >= 64*9*32) return;
    int co = idx % 32;
    int t  = idx / 32;
    int k  = t % 9;
    int ci = t / 9;
    float vz, vr;
    if (ci < 32) {
        vz = wz[(co*96 + ci)*9 + k] + wz[(co*96 + ci + 32)*9 + k];
        vr = wr[(co*96 + ci)*9 + k] + wr[(co*96 + ci + 32)*9 + k];
    } else {
        vz = wz[(co*96 + ci + 32)*9 + k];
        vr = wr[(co*96 + ci + 32)*9 + k];
    }
    wzt[idx] = vz; wrt[idx] = vr;
}

// ---------------- encoder kernels ----------------

// 7x7 stride2 pad3, 3->32ch, input normalization fused; thread: 1 px, all 32 co
__global__ void conv7s2_v2(const float* __restrict__ img, const float* __restrict__ wt,
                           const float* __restrict__ b, float* __restrict__ out) {
    int sp = blockIdx.x*256 + threadIdx.x;
    int oy = sp / W1, ox = sp % W1;
    float acc[32];
    #pragma unroll
    for (int j = 0; j < 32; ++j) acc[j] = b[j];
    for (int ci = 0; ci < 3; ++ci) {
        for (int ky = 0; ky < 7; ++ky) {
            int iy = 2*oy - 3 + ky;
            if ((unsigned)iy >= (unsigned)H0) continue;
            const float* row  = img + ci*(H0*W0) + iy*W0;
            const float* wrow = wt + (ci*49 + ky*7)*32;
            #pragma unroll
            for (int kx = 0; kx < 7; ++kx) {
                int ix = 2*ox - 3 + kx;
                if ((unsigned)ix >= (unsigned)W0) continue;
                float v = row[ix]*(2.0f/255.0f) - 1.0f;
                const float4* wp = (const float4*)(wrow + kx*32);
                #pragma unroll
                for (int j4 = 0; j4 < 8; ++j4) {
                    float4 w4 = wp[j4];
                    acc[4*j4+0] += v*w4.x; acc[4*j4+1] += v*w4.y;
                    acc[4*j4+2] += v*w4.z; acc[4*j4+3] += v*w4.w;
                }
            }
        }
    }
    #pragma unroll
    for (int j = 0; j < 32; ++j) out[j*NP1 + sp] = acc[j];
}

// partial channel stats (sum, sumsq) via atomics; grid = 32ch * 8 slices
__global__ void stats_partial_kernel(const float* __restrict__ x, int N, float* __restrict__ st) {
    int c = blockIdx.x >> 3, sl = blockIdx.x & 7;
    int chunk = N >> 3;
    const float4* p = (const float4*)(x + (size_t)c*N + (size_t)sl*chunk);
    int n4 = chunk >> 2;
    float s = 0.f, s2 = 0.f;
    for (int i = threadIdx.x; i < n4; i += 256) {
        float4 v = p[i];
        s  += v.x + v.y + v.z + v.w;
        s2 += v.x*v.x + v.y*v.y + v.z*v.z + v.w*v.w;
    }
    __shared__ float sh1[256], sh2[256];
    sh1[threadIdx.x] = s; sh2[threadIdx.x] = s2;
    __syncthreads();
    for (int o = 128; o > 0; o >>= 1) {
        if (threadIdx.x < o) { sh1[threadIdx.x] += sh1[threadIdx.x+o]; sh2[threadIdx.x] += sh2[threadIdx.x+o]; }
        __syncthreads();
    }
    if (threadIdx.x == 0) { atomicAdd(&st[2*c], sh1[0]); atomicAdd(&st[2*c+1], sh2[0]); }
}

// x = relu((x - m)*rstd), float4; grid = dim3(N/1024, 32)
__global__ void norm_relu_v2(float* __restrict__ x, const float* __restrict__ st, int N) {
    int c = blockIdx.y;
    float m    = st[2*c] / (float)N;
    float var  = st[2*c+1] / (float)N - m*m;
    float rstd = rsqrtf(var + 1e-5f);
    float4* p = (float4*)(x + (size_t)c*N);
    int i = blockIdx.x*256 + threadIdx.x;
    float4 v = p[i];
    v.x = fmaxf((v.x-m)*rstd, 0.f); v.y = fmaxf((v.y-m)*rstd, 0.f);
    v.z = fmaxf((v.z-m)*rstd, 0.f); v.w = fmaxf((v.w-m)*rstd, 0.f);
    p[i] = v;
}

// 3x3 stride2 pad1, 32->32; thread: 1 px, 8 co; grid 4*(NP2/256)
__global__ void conv3s2_v2(const float* __restrict__ in, const float* __restrict__ wt,
                           const float* __restrict__ b, float* __restrict__ out) {
    int cg = blockIdx.x / (NP2/256);
    int sp = (blockIdx.x % (NP2/256))*256 + threadIdx.x;
    int co8 = cg*8;
    int oy = sp / W2, ox = sp % W2;
    float acc[8];
    #pragma unroll
    for (int j = 0; j < 8; ++j) acc[j] = b[co8+j];
    for (int ci = 0; ci < 32; ++ci) {
        const float* ip  = in + ci*NP1;
        const float* wci = wt + ci*9*32 + co8;
        #pragma unroll
        for (int ky = 0; ky < 3; ++ky) {
            int iy = 2*oy - 1 + ky;
            if ((unsigned)iy >= (unsigned)H1) continue;
            const float* row = ip + iy*W1;
            #pragma unroll
            for (int kx = 0; kx < 3; ++kx) {
                int ix = 2*ox - 1 + kx;
                if ((unsigned)ix >= (unsigned)W1) continue;
                float v = row[ix];
                const float4* wp = (const float4*)(wci + (ky*3+kx)*32);
                float4 w0 = wp[0], w1 = wp[1];
                acc[0] += v*w0.x; acc[1] += v*w0.y; acc[2] += v*w0.z; acc[3] += v*w0.w;
                acc[4] += v*w1.x; acc[5] += v*w1.y; acc[6] += v*w1.z; acc[7] += v*w1.w;
            }
        }
    }
    #pragma unroll
    for (int j = 0; j < 8; ++j) out[(co8+j)*NP2 + sp] = acc[j];
}

// 1x1 conv 32->32, optional tanh; thread: 1 px, 8 co
__global__ void conv1x1_v2(const float* __restrict__ in, const float* __restrict__ wt,
                           const float* __restrict__ b, float* __restrict__ out, int mode) {
    int cg = blockIdx.x / (NP2/256);
    int sp = (blockIdx.x % (NP2/256))*256 + threadIdx.x;
    int co8 = cg*8;
    float acc[8];
    #pragma unroll
    for (int j = 0; j < 8; ++j) acc[j] = b[co8+j];
    for (int ci = 0; ci < 32; ++ci) {
        float v = in[ci*NP2 + sp];
        const float4* wp = (const float4*)(wt + ci*32 + co8);
        float4 w0 = wp[0], w1 = wp[1];
        acc[0] += v*w0.x; acc[1] += v*w0.y; acc[2] += v*w0.z; acc[3] += v*w0.w;
        acc[4] += v*w1.x; acc[5] += v*w1.y; acc[6] += v*w1.z; acc[7] += v*w1.w;
    }
    #pragma unroll
    for (int j = 0; j < 8; ++j) {
        float a = acc[j];
        if (mode) a = tanhf(a);
        out[(co8+j)*NP2 + sp] = a;
    }
}

// ---------------- GRU loop kernels ----------------

// feat = A*f1 + B*f2 + Cw*(f1*f2) + b (1x1); thread: 1 px, 8 co
__global__ void feat_kernel(const float* __restrict__ fmap1, const float* __restrict__ fmap2,
                            const float* __restrict__ wat, const float* __restrict__ wbt,
                            const float* __restrict__ wct, const float* __restrict__ bc,
                            float* __restrict__ feat, int d, int nblk) {
    int cg = blockIdx.x / nblk;
    int sp = (blockIdx.x % nblk)*256 + threadIdx.x;
    int Wd = W2 - d;
    int nsp = H2*Wd;
    if (sp >= nsp) return;
    int y = sp / Wd;
    int x = sp - y*Wd;
    int co8 = cg*8;
    int off = y*W2 + x;
    float acc[8];
    #pragma unroll
    for (int j = 0; j < 8; ++j) acc[j] = bc[co8+j];
    for (int ci = 0; ci < 32; ++ci) {
        float f1 = fmap1[ci*NP2 + off + d];
        float f2 = fmap2[ci*NP2 + off];
        float f12 = f1*f2;
        const float4* ap = (const float4*)(wat + ci*32 + co8);
        const float4* bp = (const float4*)(wbt + ci*32 + co8);
        const float4* cp = (const float4*)(wct + ci*32 + co8);
        float4 a0 = ap[0], a1 = ap[1];
        float4 b0 = bp[0], b1 = bp[1];
        float4 c0 = cp[0], c1 = cp[1];
        acc[0] += f1*a0.x + f2*b0.x + f12*c0.x;
        acc[1] += f1*a0.y + f2*b0.y + f12*c0.y;
        acc[2] += f1*a0.z + f2*b0.z + f12*c0.z;
        acc[3] += f1*a0.w + f2*b0.w + f12*c0.w;
        acc[4] += f1*a1.x + f2*b1.x + f12*c1.x;
        acc[5] += f1*a1.y + f2*b1.y + f12*c1.y;
        acc[6] += f1*a1.z + f2*b1.z + f12*c1.z;
        acc[7] += f1*a1.w + f2*b1.w + f12*c1.w;
    }
    #pragma unroll
    for (int j = 0; j < 8; ++j) feat[(co8+j)*NP2 + off] = acc[j];
}

// z,r 3x3 convs over [h(shifted), feat] with combined weights; 16x16 tile staged in LDS.
// thread: 1 px, 8 co (both z and r). Writes z and r*h.
__global__ void zr_kernel(const float* __restrict__ hidden, const float* __restrict__ feat,
                          const float* __restrict__ wzt, const float* __restrict__ wrt,
                          const float* __restrict__ bz, const float* __restrict__ br,
                          float* __restrict__ zbuf, float* __restrict__ rh,
                          int d, int ntile, int tiles_x) {
    __shared__ float smem[8*18*48];
    int cg   = blockIdx.x / ntile;
    int tile = blockIdx.x - cg*ntile;
    int x0 = (tile % tiles_x)*16;
    int y0 = (tile / tiles_x)*16;
    int co8 = cg*8;
    int tid = threadIdx.x;
    int tx = tid & 15, ty = tid >> 4;
    int Wd = W2 - d;
    float accz[8], accr[8];
    #pragma unroll
    for (int j = 0; j < 8; ++j) { accz[j] = bz[co8+j]; accr[j] = br[co8+j]; }
    for (int c0 = 0; c0 < 64; c0 += 8) {
        __syncthreads();
        for (int i = tid; i < 8*324; i += 256) {
            int ci = i / 324;
            int r  = i - ci*324;
            int ly = r / 18, lx = r - ly*18;
            int gy = y0 + ly - 1, gx = x0 + lx - 1;
            float v = 0.f;
            if ((unsigned)gy < (unsigned)H2 && (unsigned)gx < (unsigned)Wd) {
                int cig = c0 + ci;
                v = (cig < 32) ? hidden[cig*NP2 + gy*W2 + gx + d]
                               : feat[(cig-32)*NP2 + gy*W2 + gx];
            }
            smem[(ci*18 + ly)*48 + lx] = v;
        }
        __syncthreads();
        #pragma unroll
        for (int ci = 0; ci < 8; ++ci) {
            float v[9];
            int base = (ci*18 + ty)*48 + tx;
            #pragma unroll
            for (int dy = 0; dy < 3; ++dy) {
                v[dy*3+0] = smem[base + dy*48 + 0];
                v[dy*3+1] = smem[base + dy*48 + 1];
                v[dy*3+2] = smem[base + dy*48 + 2];
            }
            const float* wzp = wzt + (c0+ci)*9*32 + co8;
            const float* wrp = wrt + (c0+ci)*9*32 + co8;
            #pragma unroll
            for (int k = 0; k < 9; ++k) {
                float vv = v[k];
                const float4* zp = (const float4*)(wzp + k*32);
                const float4* rp = (const float4*)(wrp + k*32);
                float4 z0 = zp[0], z1 = zp[1], r0 = rp[0], r1 = rp[1];
                accz[0] += vv*z0.x; accz[1] += vv*z0.y; accz[2] += vv*z0.z; accz[3] += vv*z0.w;
                accz[4] += vv*z1.x; accz[5] += vv*z1.y; accz[6] += vv*z1.z; accz[7] += vv*z1.w;
                accr[0] += vv*r0.x; accr[1] += vv*r0.y; accr[2] += vv*r0.z; accr[3] += vv*r0.w;
                accr[4] += vv*r1.x; accr[5] += vv*r1.y; accr[6] += vv*r1.z; accr[7] += vv*r1.w;
            }
        }
    }
    int x = x0 + tx, y = y0 + ty;
    if (x < Wd) {
        int off = y*W2 + x;
        #pragma unroll
        for (int j = 0; j < 8; ++j) {
            int co = co8 + j;
            float z = 1.f/(1.f + __expf(-accz[j]));
            float r = 1.f/(1.f + __expf(-accr[j]));
            float h = hidden[co*NP2 + off + d];
            zbuf[co*NP2 + off] = z;
            rh[co*NP2 + off]   = r*h;
        }
    }
}

// q = tanh(conv3x3([r*h, h(shifted), feat], wq) + bq); same tiling as zr
__global__ void q_kernel(const float* __restrict__ hidden, const float* __restrict__ feat,
                         const float* __restrict__ rh, const float* __restrict__ wqt,
                         const float* __restrict__ bq, float* __restrict__ qbuf,
                         int d, int ntile, int tiles_x) {
    __shared__ float smem[8*18*48];
    int cg   = blockIdx.x / ntile;
    int tile = blockIdx.x - cg*ntile;
    int x0 = (tile % tiles_x)*16;
    int y0 = (tile / tiles_x)*16;
    int co8 = cg*8;
    int tid = threadIdx.x;
    int tx = tid & 15, ty = tid >> 4;
    int Wd = W2 - d;
    float acc[8];
    #pragma unroll
    for (int j = 0; j < 8; ++j) acc[j] = bq[co8+j];
    for (int c0 = 0; c0 < 96; c0 += 8) {
        __syncthreads();
        for (int i = tid; i < 8*324; i += 256) {
            int ci = i / 324;
            int r  = i - ci*324;
            int ly = r / 18, lx = r - ly*18;
            int gy = y0 + ly - 1, gx = x0 + lx - 1;
            float v = 0.f;
            if ((unsigned)gy < (unsigned)H2 && (unsigned)gx < (unsigned)Wd) {
                int cig = c0 + ci;
                v = (cig < 32) ? rh[cig*NP2 + gy*W2 + gx]
                  : (cig < 64) ? hidden[(cig-32)*NP2 + gy*W2 + gx + d]
                               : feat[(cig-64)*NP2 + gy*W2 + gx];
            }
            smem[(ci*18 + ly)*48 + lx] = v;
        }
        __syncthreads();
        #pragma unroll
        for (int ci = 0; ci < 8; ++ci) {
            float v[9];
            int base = (ci*18 + ty)*48 + tx;
            #pragma unroll
            for (int dy = 0; dy < 3; ++dy) {
                v[dy*3+0] = smem[base + dy*48 + 0];
                v[dy*3+1] = smem[base + dy*48 + 1];
                v[dy*3+2] = smem[base + dy*48 + 2];
            }
            const float* wp = wqt + (c0+ci)*9*32 + co8;
            #pragma unroll
            for (int k = 0; k < 9; ++k) {
                float vv = v[k];
                const float4* qp = (const float4*)(wp + k*32);
                float4 w0 = qp[0], w1 = qp[1];
                acc[0] += vv*w0.x; acc[1] += vv*w0.y; acc[2] += vv*w0.z; acc[3] += vv*w0.w;
                acc[4] += vv*w1.x; acc[5] += vv*w1.y; acc[6] += vv*w1.z; acc[7] += vv*w1.w;
            }
        }
    }
    int x = x0 + tx, y = y0 + ty;
    if (x < Wd) {
        int off = y*W2 + x;
        #pragma unroll
        for (int j = 0; j < 8; ++j)
            qbuf[(co8+j)*NP2 + off] = tanhf(acc[j]);
    }
}

// hidden[:, :, d:] = (1-z)*h + z*q
__global__ void update_kernel(float* __restrict__ hidden, const float* __restrict__ zbuf,
                              const float* __restrict__ qbuf, int d, int total) {
    int idx = blockIdx.x*256 + threadIdx.x;
    if (idx >= total) return;
    int Wd = W2 - d;
    int x = idx % Wd;
    int rest = idx / Wd;          // co*H2 + y
    int off = rest*W2 + x;
    float h = hidden[off + d];
    float z = zbuf[off];
    float q = qbuf[off];
    hidden[off + d] = (1.0f - z)*h + z*q;
}

// ---------------- disparity head ----------------

// 3x3 conv 32->64 + relu; thread: 1 px, 8 co; grid 8*(NP2/256)
__global__ void disp1_v2(const float* __restrict__ hidden, const float* __restrict__ wt,
                         const float* __restrict__ b, float* __restrict__ out) {
    int cg = blockIdx.x / (NP2/256);
    int sp = (blockIdx.x % (NP2/256))*256 + threadIdx.x;
    int co8 = cg*8;
    int y = sp / W2, x = sp % W2;
    float acc[8];
    #pragma unroll
    for (int j = 0; j < 8; ++j) acc[j] = b[co8+j];
    for (int ci = 0; ci < 32; ++ci) {
        const float* ip = hidden + ci*NP2;
        #pragma unroll
        for (int dy = 0; dy < 3; ++dy) {
            int ys = y + dy - 1;
            if ((unsigned)ys >= (unsigned)H2) continue;
            const float* row = ip + ys*W2;
            #pragma unroll
            for (int dx = 0; dx < 3; ++dx) {
                int xs = x + dx - 1;
                if ((unsigned)xs >= (unsigned)W2) continue;
                float v = row[xs];
                const float4* wp = (const float4*)(wt + (ci*9 + dy*3 + dx)*64 + co8);
                float4 w0 = wp[0], w1 = wp[1];
                acc[0] += v*w0.x; acc[1] += v*w0.y; acc[2] += v*w0.z; acc[3] += v*w0.w;
                acc[4] += v*w1.x; acc[5] += v*w1.y; acc[6] += v*w1.z; acc[7] += v*w1.w;
            }
        }
    }
    #pragma unroll
    for (int j = 0; j < 8; ++j) out[(co8+j)*NP2 + sp] = fmaxf(acc[j], 0.f);
}

// 3x3 conv 64->1, negate
__global__ void disp2_kernel(const float* __restrict__ in, const float* __restrict__ w,
                             const float* __restrict__ b, float* __restrict__ out) {
    __shared__ float lw[64*9];
    int sp = blockIdx.x*256 + threadIdx.x;
    for (int i = threadIdx.x; i < 576; i += 256) lw[i] = w[i];
    __syncthreads();
    int y = sp / W2, x = sp % W2;
    float acc = b[0];
    for (int ci = 0; ci < 64; ++ci) {
        const float* ip = in + ci*NP2;
        #pragma unroll
        for (int dy = 0; dy < 3; ++dy) {
            int ys = y+dy-1; if ((unsigned)ys >= (unsigned)H2) continue;
            const float* row = ip + ys*W2;
            #pragma unroll
            for (int dx = 0; dx < 3; ++dx) {
                int xs = x+dx-1; if ((unsigned)xs >= (unsigned)W2) continue;
                acc += lw[ci*9+dy*3+dx] * row[xs];
            }
        }
    }
    out[sp] = -acc;
}

// ---------------- launch ----------------

extern "C" void kernel_launch(void* const* d_in, const int* in_sizes, int n_in,
                              void* d_out, int out_size, void* d_ws, size_t ws_size,
                              hipStream_t stream) {
    const float* image1   = (const float*)d_in[0];
    const float* image2   = (const float*)d_in[1];
    const float* fnet_w1  = (const float*)d_in[2];
    const float* fnet_b1  = (const float*)d_in[3];
    const float* fnet_w2  = (const float*)d_in[4];
    const float* fnet_b2  = (const float*)d_in[5];
    const float* fnet_w3  = (const float*)d_in[6];
    const float* fnet_b3  = (const float*)d_in[7];
    const float* cnet_w1  = (const float*)d_in[8];
    const float* cnet_b1  = (const float*)d_in[9];
    const float* cnet_w2  = (const float*)d_in[10];
    const float* cnet_b2  = (const float*)d_in[11];
    const float* cnet_w3  = (const float*)d_in[12];
    const float* cnet_b3  = (const float*)d_in[13];
    const float* bform_a  = (const float*)d_in[14];
    const float* bform_b  = (const float*)d_in[15];
    const float* bform_cd_w = (const float*)d_in[16];
    const float* bform_cd_b = (const float*)d_in[17];
    const float* gru_wz   = (const float*)d_in[18];
    const float* gru_bz   = (const float*)d_in[19];
    const float* gru_wr   = (const float*)d_in[20];
    const float* gru_br   = (const float*)d_in[21];
    const float* gru_wq   = (const float*)d_in[22];
    const float* gru_bq   = (const float*)d_in[23];
    const float* disp_w1  = (const float*)d_in[24];
    const float* disp_b1  = (const float*)d_in[25];
    const float* disp_w2  = (const float*)d_in[26];
    const float* disp_b2  = (const float*)d_in[27];

    float* ws = (float*)d_ws;
    size_t o = 0;
    float* e1     = ws + o; o += (size_t)32*NP1;
    float* e2     = ws + o; o += (size_t)32*NP2;
    float* fmap1  = ws + o; o += (size_t)32*NP2;
    float* fmap2  = ws + o; o += (size_t)32*NP2;
    float* hidden = ws + o; o += (size_t)32*NP2;
    float* feat   = ws + o; o += (size_t)32*NP2;
    float* zbuf   = ws + o; o += (size_t)32*NP2;
    float* rhbuf  = ws + o; o += (size_t)32*NP2;
    float* qbuf   = ws + o; o += (size_t)32*NP2;
    float* stats  = ws + o; o += 384;        // 6 sites x 32ch x {sum,sumsq}
    float* wzt    = ws + o; o += 64*9*32;
    float* wrt    = ws + o; o += 64*9*32;
    float* wqt    = ws + o; o += 96*9*32;
    float* we1f   = ws + o; o += 3*49*32;
    float* we1c   = ws + o; o += 3*49*32;
    float* we2f   = ws + o; o += 32*9*32;
    float* we2c   = ws + o; o += 32*9*32;
    float* w3f    = ws + o; o += 32*32;
    float* w3c    = ws + o; o += 32*32;
    float* wat    = ws + o; o += 32*32;
    float* wbt    = ws + o; o += 32*32;
    float* wct    = ws + o; o += 32*32;
    float* wd1t   = ws + o; o += 32*9*64;
    float* disp1buf = e1;   // e1 dead after encoders; 64*NP2 <= 32*NP1

    // --- prep: zero stats, transpose weights ---
    zero_stats_kernel<<<2, 256, 0, stream>>>(stats, 384);
    transpose_w_kernel<<<(3*49*32+255)/256, 256, 0, stream>>>(fnet_w1, we1f, 3, 49, 32);
    transpose_w_kernel<<<(3*49*32+255)/256, 256, 0, stream>>>(cnet_w1, we1c, 3, 49, 32);
    transpose_w_kernel<<<(32*9*32+255)/256, 256, 0, stream>>>(fnet_w2, we2f, 32, 9, 32);
    transpose_w_kernel<<<(32*9*32+255)/256, 256, 0, stream>>>(cnet_w2, we2c, 32, 9, 32);
    transpose_w_kernel<<<4, 256, 0, stream>>>(fnet_w3, w3f, 32, 1, 32);
    transpose_w_kernel<<<4, 256, 0, stream>>>(cnet_w3, w3c, 32, 1, 32);
    transpose_w_kernel<<<4, 256, 0, stream>>>(bform_a, wat, 32, 1, 32);
    transpose_w_kernel<<<4, 256, 0, stream>>>(bform_b, wbt, 32, 1, 32);
    transpose_w_kernel<<<4, 256, 0, stream>>>(bform_cd_w, wct, 32, 1, 32);
    transpose_w_kernel<<<(96*9*32+255)/256, 256, 0, stream>>>(gru_wq, wqt, 96, 9, 32);
    transpose_w_kernel<<<(32*9*64+255)/256, 256, 0, stream>>>(disp_w1, wd1t, 32, 9, 64);
    prep_zr_t_kernel<<<(64*9*32+255)/256, 256, 0, stream>>>(gru_wz, gru_wr, wzt, wrt);

    // --- encoders (B=1: inorm == bnorm) ---
    auto encoder = [&](const float* img, const float* w1t, const float* b1,
                       const float* w2t, const float* b2,
                       const float* w3t, const float* b3, float* dst, int mode,
                       float* st1, float* st2) {
        conv7s2_v2<<<NP1/256, 256, 0, stream>>>(img, w1t, b1, e1);
        stats_partial_kernel<<<256, 256, 0, stream>>>(e1, NP1, st1);
        norm_relu_v2<<<dim3(NP1/1024, 32), 256, 0, stream>>>(e1, st1, NP1);
        conv3s2_v2<<<4*(NP2/256), 256, 0, stream>>>(e1, w2t, b2, e2);
        stats_partial_kernel<<<256, 256, 0, stream>>>(e2, NP2, st2);
        norm_relu_v2<<<dim3(NP2/1024, 32), 256, 0, stream>>>(e2, st2, NP2);
        conv1x1_v2<<<4*(NP2/256), 256, 0, stream>>>(e2, w3t, b3, dst, mode);
    };
    encoder(image1, we1f, fnet_b1, we2f, fnet_b2, w3f, fnet_b3, fmap1, 0, stats+0,   stats+64);
    encoder(image2, we1f, fnet_b1, we2f, fnet_b2, w3f, fnet_b3, fmap2, 0, stats+128, stats+192);
    encoder(image1, we1c, cnet_b1, we2c, cnet_b2, w3c, cnet_b3, hidden, 1, stats+256, stats+320);

    // --- sequential GRU sweep over disparities ---
    for (int d = 0; d < ND; ++d) {
        int Wd = W2 - d;
        int nsp = H2*Wd;
        int nblk = (nsp + 255)/256;
        int tiles_x = (Wd + 15)/16;
        int ntile = tiles_x*6;   // H2/16 = 6
        feat_kernel<<<4*nblk, 256, 0, stream>>>(fmap1, fmap2, wat, wbt, wct, bform_cd_b,
                                                feat, d, nblk);
        zr_kernel<<<4*ntile, 256, 0, stream>>>(hidden, feat, wzt, wrt, gru_bz, gru_br,
                                               zbuf, rhbuf, d, ntile, tiles_x);
        q_kernel<<<4*ntile, 256, 0, stream>>>(hidden, feat, rhbuf, wqt, gru_bq, qbuf,
                                              d, ntile, tiles_x);
        int tot = 32*nsp;
        update_kernel<<<(tot + 255)/256, 256, 0, stream>>>(hidden, zbuf, qbuf, d, tot);
    }

    // --- disparity head ---
    disp1_v2<<<8*(NP2/256), 256, 0, stream>>>(hidden, wd1t, disp_b1, disp1buf);
    disp2_kernel<<<NP2/256, 256, 0, stream>>>(disp1buf, disp_w2, disp_b2, (float*)d_out);
}

// Round 4
// 4792.183 us; speedup vs baseline: 2.5844x; 2.3775x over previous
//
#include <hip/hip_runtime.h>
#include <math.h>

#define H0 384
#define W0 640
#define H1 192
#define W1 320
#define H2 96
#define W2 160
#define NP1 (H1*W1)   /* 61440 */
#define NP2 (H2*W2)   /* 15360 */
#define ND  48        /* MAX_DISP/4 */
#define NBLK2 (NP2/256)  /* 60 */
#define CHW ((size_t)32*NP2)

// ---------------- prep kernels ----------------

__global__ void zero_stats_kernel(float* __restrict__ s, int n) {
    int i = blockIdx.x*256 + threadIdx.x;
    if (i < n) s[i] = 0.f;
}

// out[(ci*K + k)*CO + co] = in[(co*CI + ci)*K + k]
__global__ void transpose_w_kernel(const float* __restrict__ in, float* __restrict__ out,
                                   int CI, int K, int CO) {
    int idx = blockIdx.x*256 + threadIdx.x;
    int total = CI*K*CO;
    if (idx >= total) return;
    int co = idx % CO;
    int t  = idx / CO;
    int k  = t % K;
    int ci = t / K;
    out[idx] = in[(co*CI + ci)*K + k];
}

// packed z/r weights for 2-co groups: wpk[cg][ci<64][k][{z co0, z co1, r co0, r co1}]
// combined for hx=[h,h,feat]: ci<32 -> w[:,ci]+w[:,ci+32]; ci>=32 -> w[:,ci+32]
__global__ void prep_zr_pk(const float* __restrict__ wz, const float* __restrict__ wr,
                           float4* __restrict__ wpk) {
    int idx = blockIdx.x*256 + threadIdx.x;   // 16*64*9 = 9216
    if (idx >= 16*64*9) return;
    int k  = idx % 9;
    int ci = (idx/9) % 64;
    int cg = idx / (9*64);
    int co0 = cg*2, co1 = co0 + 1;
    float z0, z1, r0, r1;
    if (ci < 32) {
        z0 = wz[(co0*96 + ci)*9 + k] + wz[(co0*96 + ci + 32)*9 + k];
        z1 = wz[(co1*96 + ci)*9 + k] + wz[(co1*96 + ci + 32)*9 + k];
        r0 = wr[(co0*96 + ci)*9 + k] + wr[(co0*96 + ci + 32)*9 + k];
        r1 = wr[(co1*96 + ci)*9 + k] + wr[(co1*96 + ci + 32)*9 + k];
    } else {
        z0 = wz[(co0*96 + ci + 32)*9 + k];
        z1 = wz[(co1*96 + ci + 32)*9 + k];
        r0 = wr[(co0*96 + ci + 32)*9 + k];
        r1 = wr[(co1*96 + ci + 32)*9 + k];
    }
    wpk[idx] = make_float4(z0, z1, r0, r1);
}

// packed q weights: qpk[cg][ci<96][k][{co0, co1}]
__global__ void prep_q_pk(const float* __restrict__ wq, float2* __restrict__ qpk) {
    int idx = blockIdx.x*256 + threadIdx.x;   // 16*96*9 = 13824
    if (idx >= 16*96*9) return;
    int k  = idx % 9;
    int ci = (idx/9) % 96;
    int cg = idx / (9*96);
    qpk[idx] = make_float2(wq[((cg*2)*96 + ci)*9 + k], wq[((cg*2+1)*96 + ci)*9 + k]);
}

// ---------------- encoder kernels ----------------

__global__ void conv7s2_v2(const float* __restrict__ img, const float* __restrict__ wt,
                           const float* __restrict__ b, float* __restrict__ out) {
    int sp = blockIdx.x*256 + threadIdx.x;
    int oy = sp / W1, ox = sp % W1;
    float acc[32];
    #pragma unroll
    for (int j = 0; j < 32; ++j) acc[j] = b[j];
    for (int ci = 0; ci < 3; ++ci) {
        for (int ky = 0; ky < 7; ++ky) {
            int iy = 2*oy - 3 + ky;
            if ((unsigned)iy >= (unsigned)H0) continue;
            const float* row  = img + ci*(H0*W0) + iy*W0;
            const float* wrow = wt + (ci*49 + ky*7)*32;
            #pragma unroll
            for (int kx = 0; kx < 7; ++kx) {
                int ix = 2*ox - 3 + kx;
                if ((unsigned)ix >= (unsigned)W0) continue;
                float v = row[ix]*(2.0f/255.0f) - 1.0f;
                const float4* wp = (const float4*)(wrow + kx*32);
                #pragma unroll
                for (int j4 = 0; j4 < 8; ++j4) {
                    float4 w4 = wp[j4];
                    acc[4*j4+0] += v*w4.x; acc[4*j4+1] += v*w4.y;
                    acc[4*j4+2] += v*w4.z; acc[4*j4+3] += v*w4.w;
                }
            }
        }
    }
    #pragma unroll
    for (int j = 0; j < 32; ++j) out[j*NP1 + sp] = acc[j];
}

__global__ void stats_partial_kernel(const float* __restrict__ x, int N, float* __restrict__ st) {
    int c = blockIdx.x >> 3, sl = blockIdx.x & 7;
    int chunk = N >> 3;
    const float4* p = (const float4*)(x + (size_t)c*N + (size_t)sl*chunk);
    int n4 = chunk >> 2;
    float s = 0.f, s2 = 0.f;
    for (int i = threadIdx.x; i < n4; i += 256) {
        float4 v = p[i];
        s  += v.x + v.y + v.z + v.w;
        s2 += v.x*v.x + v.y*v.y + v.z*v.z + v.w*v.w;
    }
    __shared__ float sh1[256], sh2[256];
    sh1[threadIdx.x] = s; sh2[threadIdx.x] = s2;
    __syncthreads();
    for (int o = 128; o > 0; o >>= 1) {
        if (threadIdx.x < o) { sh1[threadIdx.x] += sh1[threadIdx.x+o]; sh2[threadIdx.x] += sh2[threadIdx.x+o]; }
        __syncthreads();
    }
    if (threadIdx.x == 0) { atomicAdd(&st[2*c], sh1[0]); atomicAdd(&st[2*c+1], sh2[0]); }
}

__global__ void norm_relu_v2(float* __restrict__ x, const float* __restrict__ st, int N) {
    int c = blockIdx.y;
    float m    = st[2*c] / (float)N;
    float var  = st[2*c+1] / (float)N - m*m;
    float rstd = rsqrtf(var + 1e-5f);
    float4* p = (float4*)(x + (size_t)c*N);
    int i = blockIdx.x*256 + threadIdx.x;
    float4 v = p[i];
    v.x = fmaxf((v.x-m)*rstd, 0.f); v.y = fmaxf((v.y-m)*rstd, 0.f);
    v.z = fmaxf((v.z-m)*rstd, 0.f); v.w = fmaxf((v.w-m)*rstd, 0.f);
    p[i] = v;
}

__global__ void conv3s2_v2(const float* __restrict__ in, const float* __restrict__ wt,
                           const float* __restrict__ b, float* __restrict__ out) {
    int cg = blockIdx.x / (NP2/256);
    int sp = (blockIdx.x % (NP2/256))*256 + threadIdx.x;
    int co8 = cg*8;
    int oy = sp / W2, ox = sp % W2;
    float acc[8];
    #pragma unroll
    for (int j = 0; j < 8; ++j) acc[j] = b[co8+j];
    for (int ci = 0; ci < 32; ++ci) {
        const float* ip  = in + ci*NP1;
        const float* wci = wt + ci*9*32 + co8;
        #pragma unroll
        for (int ky = 0; ky < 3; ++ky) {
            int iy = 2*oy - 1 + ky;
            if ((unsigned)iy >= (unsigned)H1) continue;
            const float* row = ip + iy*W1;
            #pragma unroll
            for (int kx = 0; kx < 3; ++kx) {
                int ix = 2*ox - 1 + kx;
                if ((unsigned)ix >= (unsigned)W1) continue;
                float v = row[ix];
                const float4* wp = (const float4*)(wci + (ky*3+kx)*32);
                float4 w0 = wp[0], w1 = wp[1];
                acc[0] += v*w0.x; acc[1] += v*w0.y; acc[2] += v*w0.z; acc[3] += v*w0.w;
                acc[4] += v*w1.x; acc[5] += v*w1.y; acc[6] += v*w1.z; acc[7] += v*w1.w;
            }
        }
    }
    #pragma unroll
    for (int j = 0; j < 8; ++j) out[(co8+j)*NP2 + sp] = acc[j];
}

__global__ void conv1x1_v2(const float* __restrict__ in, const float* __restrict__ wt,
                           const float* __restrict__ b, float* __restrict__ out, int mode) {
    int cg = blockIdx.x / (NP2/256);
    int sp = (blockIdx.x % (NP2/256))*256 + threadIdx.x;
    int co8 = cg*8;
    float acc[8];
    #pragma unroll
    for (int j = 0; j < 8; ++j) acc[j] = b[co8+j];
    for (int ci = 0; ci < 32; ++ci) {
        float v = in[ci*NP2 + sp];
        const float4* wp = (const float4*)(wt + ci*32 + co8);
        float4 w0 = wp[0], w1 = wp[1];
        acc[0] += v*w0.x; acc[1] += v*w0.y; acc[2] += v*w0.z; acc[3] += v*w0.w;
        acc[4] += v*w1.x; acc[5] += v*w1.y; acc[6] += v*w1.z; acc[7] += v*w1.w;
    }
    #pragma unroll
    for (int j = 0; j < 8; ++j) {
        float a = acc[j];
        if (mode) a = tanhf(a);
        out[(co8+j)*NP2 + sp] = a;
    }
}

// ---------------- feat precompute ----------------

// feat[d][co][y*W2+x] for x < W2-d; grid = nd*4*NBLK2; thread: 1 px, 8 co
__global__ void featall_kernel(const float* __restrict__ fmap1, const float* __restrict__ fmap2,
                               const float* __restrict__ wat, const float* __restrict__ wbt,
                               const float* __restrict__ wct, const float* __restrict__ bc,
                               float* __restrict__ featall, int d0) {
    int bid = blockIdx.x;
    int dsl = bid / (4*NBLK2);
    int rem = bid % (4*NBLK2);
    int cg  = rem / NBLK2;
    int sp  = (rem % NBLK2)*256 + threadIdx.x;
    int d = d0 + dsl;
    int Wd = W2 - d;
    int x = sp % W2;
    if (x >= Wd) return;
    int co8 = cg*8;
    float acc[8];
    #pragma unroll
    for (int j = 0; j < 8; ++j) acc[j] = bc[co8+j];
    for (int ci = 0; ci < 32; ++ci) {
        float f1 = fmap1[ci*NP2 + sp + d];
        float f2 = fmap2[ci*NP2 + sp];
        float f12 = f1*f2;
        const float4* ap = (const float4*)(wat + ci*32 + co8);
        const float4* bp = (const float4*)(wbt + ci*32 + co8);
        const float4* cp = (const float4*)(wct + ci*32 + co8);
        float4 a0 = ap[0], a1 = ap[1];
        float4 b0 = bp[0], b1 = bp[1];
        float4 c0 = cp[0], c1 = cp[1];
        acc[0] += f1*a0.x + f2*b0.x + f12*c0.x;
        acc[1] += f1*a0.y + f2*b0.y + f12*c0.y;
        acc[2] += f1*a0.z + f2*b0.z + f12*c0.z;
        acc[3] += f1*a0.w + f2*b0.w + f12*c0.w;
        acc[4] += f1*a1.x + f2*b1.x + f12*c1.x;
        acc[5] += f1*a1.y + f2*b1.y + f12*c1.y;
        acc[6] += f1*a1.z + f2*b1.z + f12*c1.z;
        acc[7] += f1*a1.w + f2*b1.w + f12*c1.w;
    }
    float* dst = featall + (size_t)dsl*CHW;
    #pragma unroll
    for (int j = 0; j < 8; ++j) dst[(co8+j)*NP2 + sp] = acc[j];
}

// ---------------- GRU loop kernels ----------------

// z,r 3x3 convs over [h(shifted,+h dup), feat]; thread: 1 px x 2 co; 960 blocks
__global__ __launch_bounds__(256, 4)
void zr_v3(const float* __restrict__ hidden, const float* __restrict__ feat,
           const float4* __restrict__ wpk, const float* __restrict__ bz,
           const float* __restrict__ br, float* __restrict__ zbuf,
           float* __restrict__ rh, int d) {
    __shared__ float4 lw[64*9];
    int cg = blockIdx.x / NBLK2;
    int sp = (blockIdx.x % NBLK2)*256 + threadIdx.x;
    for (int i = threadIdx.x; i < 576; i += 256) lw[i] = wpk[cg*576 + i];
    __syncthreads();
    int Wd = W2 - d;
    int x = sp % W2;
    int y = sp / W2;
    if (x >= Wd) return;
    int co0 = cg*2;
    float az0 = bz[co0], az1 = bz[co0+1];
    float ar0 = br[co0], ar1 = br[co0+1];
    int y0ok = (y > 0), y2ok = (y < H2-1);
    int x0ok = (x > 0), x2ok = (x < Wd-1);
    const float* src = hidden + d;
    const float4* wp = lw;
    #pragma unroll 1
    for (int pass = 0; pass < 2; ++pass) {
        #pragma unroll 1
        for (int ci = 0; ci < 32; ++ci) {
            const float* ip = src + (size_t)ci*NP2 + sp;
            float v[9];
            v[0] = (y0ok & x0ok) ? ip[-W2-1] : 0.f;
            v[1] =  y0ok         ? ip[-W2  ] : 0.f;
            v[2] = (y0ok & x2ok) ? ip[-W2+1] : 0.f;
            v[3] =  x0ok         ? ip[-1]    : 0.f;
            v[4] =                 ip[0];
            v[5] =  x2ok         ? ip[1]     : 0.f;
            v[6] = (y2ok & x0ok) ? ip[ W2-1] : 0.f;
            v[7] =  y2ok         ? ip[ W2  ] : 0.f;
            v[8] = (y2ok & x2ok) ? ip[ W2+1] : 0.f;
            #pragma unroll
            for (int k = 0; k < 9; ++k) {
                float4 w = wp[k];
                float vv = v[k];
                az0 += vv*w.x; az1 += vv*w.y;
                ar0 += vv*w.z; ar1 += vv*w.w;
            }
            wp += 9;
        }
        src = feat;
    }
    float z0 = 1.f/(1.f + __expf(-az0));
    float z1 = 1.f/(1.f + __expf(-az1));
    float r0 = 1.f/(1.f + __expf(-ar0));
    float r1 = 1.f/(1.f + __expf(-ar1));
    float h0 = hidden[(size_t)co0*NP2 + sp + d];
    float h1 = hidden[(size_t)(co0+1)*NP2 + sp + d];
    zbuf[(size_t)co0*NP2 + sp]     = z0;
    zbuf[(size_t)(co0+1)*NP2 + sp] = z1;
    rh[(size_t)co0*NP2 + sp]       = r0*h0;
    rh[(size_t)(co0+1)*NP2 + sp]   = r1*h1;
}

// q = tanh(conv3x3([r*h, h(shifted), feat])); thread: 1 px x 2 co; 960 blocks
__global__ __launch_bounds__(256, 4)
void q_v3(const float* __restrict__ hidden, const float* __restrict__ feat,
          const float* __restrict__ rh, const float2* __restrict__ qpk,
          const float* __restrict__ bq, float* __restrict__ qbuf, int d) {
    __shared__ float2 lw[96*9];
    int cg = blockIdx.x / NBLK2;
    int sp = (blockIdx.x % NBLK2)*256 + threadIdx.x;
    for (int i = threadIdx.x; i < 864; i += 256) lw[i] = qpk[cg*864 + i];
    __syncthreads();
    int Wd = W2 - d;
    int x = sp % W2;
    int y = sp / W2;
    if (x >= Wd) return;
    int co0 = cg*2;
    float a0 = bq[co0], a1 = bq[co0+1];
    int y0ok = (y > 0), y2ok = (y < H2-1);
    int x0ok = (x > 0), x2ok = (x < Wd-1);
    const float2* wp = lw;
    const float* srcs[3];
    srcs[0] = rh; srcs[1] = hidden + d; srcs[2] = feat;
    #pragma unroll 1
    for (int pass = 0; pass < 3; ++pass) {
        const float* src = srcs[pass];
        #pragma unroll 1
        for (int ci = 0; ci < 32; ++ci) {
            const float* ip = src + (size_t)ci*NP2 + sp;
            float v[9];
            v[0] = (y0ok & x0ok) ? ip[-W2-1] : 0.f;
            v[1] =  y0ok         ? ip[-W2  ] : 0.f;
            v[2] = (y0ok & x2ok) ? ip[-W2+1] : 0.f;
            v[3] =  x0ok         ? ip[-1]    : 0.f;
            v[4] =                 ip[0];
            v[5] =  x2ok         ? ip[1]     : 0.f;
            v[6] = (y2ok & x0ok) ? ip[ W2-1] : 0.f;
            v[7] =  y2ok         ? ip[ W2  ] : 0.f;
            v[8] = (y2ok & x2ok) ? ip[ W2+1] : 0.f;
            #pragma unroll
            for (int k = 0; k < 9; ++k) {
                float2 w = wp[k];
                float vv = v[k];
                a0 += vv*w.x; a1 += vv*w.y;
            }
            wp += 9;
        }
    }
    qbuf[(size_t)co0*NP2 + sp]     = tanhf(a0);
    qbuf[(size_t)(co0+1)*NP2 + sp] = tanhf(a1);
}

// hidden[:, :, d:] = (1-z)*h + z*q
__global__ void update_kernel(float* __restrict__ hidden, const float* __restrict__ zbuf,
                              const float* __restrict__ qbuf, int d, int total) {
    int idx = blockIdx.x*256 + threadIdx.x;
    if (idx >= total) return;
    int Wd = W2 - d;
    int x = idx % Wd;
    int rest = idx / Wd;          // co*H2 + y
    int off = rest*W2 + x;
    float h = hidden[off + d];
    float z = zbuf[off];
    float q = qbuf[off];
    hidden[off + d] = (1.0f - z)*h + z*q;
}

// ---------------- disparity head ----------------

__global__ void disp1_v2(const float* __restrict__ hidden, const float* __restrict__ wt,
                         const float* __restrict__ b, float* __restrict__ out) {
    int cg = blockIdx.x / (NP2/256);
    int sp = (blockIdx.x % (NP2/256))*256 + threadIdx.x;
    int co8 = cg*8;
    int y = sp / W2, x = sp % W2;
    float acc[8];
    #pragma unroll
    for (int j = 0; j < 8; ++j) acc[j] = b[co8+j];
    for (int ci = 0; ci < 32; ++ci) {
        const float* ip = hidden + ci*NP2;
        #pragma unroll
        for (int dy = 0; dy < 3; ++dy) {
            int ys = y + dy - 1;
            if ((unsigned)ys >= (unsigned)H2) continue;
            const float* row = ip + ys*W2;
            #pragma unroll
            for (int dx = 0; dx < 3; ++dx) {
                int xs = x + dx - 1;
                if ((unsigned)xs >= (unsigned)W2) continue;
                float v = row[xs];
                const float4* wp = (const float4*)(wt + (ci*9 + dy*3 + dx)*64 + co8);
                float4 w0 = wp[0], w1 = wp[1];
                acc[0] += v*w0.x; acc[1] += v*w0.y; acc[2] += v*w0.z; acc[3] += v*w0.w;
                acc[4] += v*w1.x; acc[5] += v*w1.y; acc[6] += v*w1.z; acc[7] += v*w1.w;
            }
        }
    }
    #pragma unroll
    for (int j = 0; j < 8; ++j) out[(co8+j)*NP2 + sp] = fmaxf(acc[j], 0.f);
}

__global__ void disp2_kernel(const float* __restrict__ in, const float* __restrict__ w,
                             const float* __restrict__ b, float* __restrict__ out) {
    __shared__ float lw[64*9];
    int sp = blockIdx.x*256 + threadIdx.x;
    for (int i = threadIdx.x; i < 576; i += 256) lw[i] = w[i];
    __syncthreads();
    int y = sp / W2, x = sp % W2;
    float acc = b[0];
    for (int ci = 0; ci < 64; ++ci) {
        const float* ip = in + ci*NP2;
        #pragma unroll
        for (int dy = 0; dy < 3; ++dy) {
            int ys = y+dy-1; if ((unsigned)ys >= (unsigned)H2) continue;
            const float* row = ip + ys*W2;
            #pragma unroll
            for (int dx = 0; dx < 3; ++dx) {
                int xs = x+dx-1; if ((unsigned)xs >= (unsigned)W2) continue;
                acc += lw[ci*9+dy*3+dx] * row[xs];
            }
        }
    }
    out[sp] = -acc;
}

// ---------------- launch ----------------

extern "C" void kernel_launch(void* const* d_in, const int* in_sizes, int n_in,
                              void* d_out, int out_size, void* d_ws, size_t ws_size,
                              hipStream_t stream) {
    const float* image1   = (const float*)d_in[0];
    const float* image2   = (const float*)d_in[1];
    const float* fnet_w1  = (const float*)d_in[2];
    const float* fnet_b1  = (const float*)d_in[3];
    const float* fnet_w2  = (const float*)d_in[4];
    const float* fnet_b2  = (const float*)d_in[5];
    const float* fnet_w3  = (const float*)d_in[6];
    const float* fnet_b3  = (const float*)d_in[7];
    const float* cnet_w1  = (const float*)d_in[8];
    const float* cnet_b1  = (const float*)d_in[9];
    const float* cnet_w2  = (const float*)d_in[10];
    const float* cnet_b2  = (const float*)d_in[11];
    const float* cnet_w3  = (const float*)d_in[12];
    const float* cnet_b3  = (const float*)d_in[13];
    const float* bform_a  = (const float*)d_in[14];
    const float* bform_b  = (const float*)d_in[15];
    const float* bform_cd_w = (const float*)d_in[16];
    const float* bform_cd_b = (const float*)d_in[17];
    const float* gru_wz   = (const float*)d_in[18];
    const float* gru_bz   = (const float*)d_in[19];
    const float* gru_wr   = (const float*)d_in[20];
    const float* gru_br   = (const float*)d_in[21];
    const float* gru_wq   = (const float*)d_in[22];
    const float* gru_bq   = (const float*)d_in[23];
    const float* disp_w1  = (const float*)d_in[24];
    const float* disp_b1  = (const float*)d_in[25];
    const float* disp_w2  = (const float*)d_in[26];
    const float* disp_b2  = (const float*)d_in[27];

    float* ws = (float*)d_ws;
    size_t o = 0;
    float* e1     = ws + o; o += (size_t)32*NP1;
    float* e2     = ws + o; o += CHW;
    float* fmap1  = ws + o; o += CHW;
    float* fmap2  = ws + o; o += CHW;
    float* hidden = ws + o; o += CHW;
    float* zbuf   = ws + o; o += CHW;
    float* rhbuf  = ws + o; o += CHW;
    float* qbuf   = ws + o; o += CHW;
    float* stats  = ws + o; o += 384;
    float* wzrpk  = ws + o; o += 16*64*9*4;
    float* wqpk   = ws + o; o += 16*96*9*2;
    float* we1f   = ws + o; o += 3*49*32;
    float* we1c   = ws + o; o += 3*49*32;
    float* we2f   = ws + o; o += 32*9*32;
    float* we2c   = ws + o; o += 32*9*32;
    float* w3f    = ws + o; o += 32*32;
    float* w3c    = ws + o; o += 32*32;
    float* wat    = ws + o; o += 32*32;
    float* wbt    = ws + o; o += 32*32;
    float* wct    = ws + o; o += 32*32;
    float* wd1t   = ws + o; o += 32*9*64;
    float* featall = ws + o;              // 48*CHW if it fits, else 1*CHW
    bool fullFeat = ws_size >= (o + (size_t)ND*CHW) * sizeof(float);
    float* disp1buf = e1;   // e1 dead after encoders; 64*NP2 <= 32*NP1

    // --- prep ---
    zero_stats_kernel<<<2, 256, 0, stream>>>(stats, 384);
    transpose_w_kernel<<<(3*49*32+255)/256, 256, 0, stream>>>(fnet_w1, we1f, 3, 49, 32);
    transpose_w_kernel<<<(3*49*32+255)/256, 256, 0, stream>>>(cnet_w1, we1c, 3, 49, 32);
    transpose_w_kernel<<<(32*9*32+255)/256, 256, 0, stream>>>(fnet_w2, we2f, 32, 9, 32);
    transpose_w_kernel<<<(32*9*32+255)/256, 256, 0, stream>>>(cnet_w2, we2c, 32, 9, 32);
    transpose_w_kernel<<<4, 256, 0, stream>>>(fnet_w3, w3f, 32, 1, 32);
    transpose_w_kernel<<<4, 256, 0, stream>>>(cnet_w3, w3c, 32, 1, 32);
    transpose_w_kernel<<<4, 256, 0, stream>>>(bform_a, wat, 32, 1, 32);
    transpose_w_kernel<<<4, 256, 0, stream>>>(bform_b, wbt, 32, 1, 32);
    transpose_w_kernel<<<4, 256, 0, stream>>>(bform_cd_w, wct, 32, 1, 32);
    transpose_w_kernel<<<(32*9*64+255)/256, 256, 0, stream>>>(disp_w1, wd1t, 32, 9, 64);
    prep_zr_pk<<<(16*64*9+255)/256, 256, 0, stream>>>(gru_wz, gru_wr, (float4*)wzrpk);
    prep_q_pk<<<(16*96*9+255)/256, 256, 0, stream>>>(gru_wq, (float2*)wqpk);

    // --- encoders (B=1: inorm == bnorm) ---
    auto encoder = [&](const float* img, const float* w1t, const float* b1,
                       const float* w2t, const float* b2,
                       const float* w3t, const float* b3, float* dst, int mode,
                       float* st1, float* st2) {
        conv7s2_v2<<<NP1/256, 256, 0, stream>>>(img, w1t, b1, e1);
        stats_partial_kernel<<<256, 256, 0, stream>>>(e1, NP1, st1);
        norm_relu_v2<<<dim3(NP1/1024, 32), 256, 0, stream>>>(e1, st1, NP1);
        conv3s2_v2<<<4*(NP2/256), 256, 0, stream>>>(e1, w2t, b2, e2);
        stats_partial_kernel<<<256, 256, 0, stream>>>(e2, NP2, st2);
        norm_relu_v2<<<dim3(NP2/1024, 32), 256, 0, stream>>>(e2, st2, NP2);
        conv1x1_v2<<<4*(NP2/256), 256, 0, stream>>>(e2, w3t, b3, dst, mode);
    };
    encoder(image1, we1f, fnet_b1, we2f, fnet_b2, w3f, fnet_b3, fmap1, 0, stats+0,   stats+64);
    encoder(image2, we1f, fnet_b1, we2f, fnet_b2, w3f, fnet_b3, fmap2, 0, stats+128, stats+192);
    encoder(image1, we1c, cnet_b1, we2c, cnet_b2, w3c, cnet_b3, hidden, 1, stats+256, stats+320);

    // --- feat precompute (all 48 slices if workspace allows) ---
    if (fullFeat) {
        featall_kernel<<<ND*4*NBLK2, 256, 0, stream>>>(fmap1, fmap2, wat, wbt, wct,
                                                       bform_cd_b, featall, 0);
    }

    // --- sequential GRU sweep over disparities ---
    for (int d = 0; d < ND; ++d) {
        int Wd = W2 - d;
        int nsp = H2*Wd;
        const float* featd;
        if (fullFeat) {
            featd = featall + (size_t)d*CHW;
        } else {
            featall_kernel<<<4*NBLK2, 256, 0, stream>>>(fmap1, fmap2, wat, wbt, wct,
                                                        bform_cd_b, featall, d);
            featd = featall;
        }
        zr_v3<<<16*NBLK2, 256, 0, stream>>>(hidden, featd, (const float4*)wzrpk,
                                            gru_bz, gru_br, zbuf, rhbuf, d);
        q_v3<<<16*NBLK2, 256, 0, stream>>>(hidden, featd, rhbuf, (const float2*)wqpk,
                                           gru_bq, qbuf, d);
        int tot = 32*nsp;
        update_kernel<<<(tot + 255)/256, 256, 0, stream>>>(hidden, zbuf, qbuf, d, tot);
    }

    // --- disparity head ---
    disp1_v2<<<8*(NP2/256), 256, 0, stream>>>(hidden, wd1t, disp_b1, disp1buf);
    disp2_kernel<<<NP2/256, 256, 0, stream>>>(disp1buf, disp_w2, disp_b2, (float*)d_out);
}